// Round 1
// baseline (107.338 us; speedup 1.0000x reference)
//
#include <hip/hip_runtime.h>

// SpatioTemporalGCN: B=64, T=12, N=1024, Ci=64, E=16, K=3, H=192, O=64
// out(b,n,:) = [l2norm(gconv) | l2norm(aconv) | l2norm(wconv)] + bias(n,:)

typedef __attribute__((ext_vector_type(4))) float f32x4;
typedef __attribute__((ext_vector_type(8))) short short8;

#define DEVI static __device__ __forceinline__

DEVI float bf2f(short u) {
    unsigned int x = ((unsigned int)(unsigned short)u) << 16;
    return __builtin_bit_cast(float, x);
}
DEVI short f2bf(float f) {
    unsigned int x = __builtin_bit_cast(unsigned int, f);
    x = (x + 0x7FFFu + ((x >> 16) & 1u)) >> 16;  // RNE
    return (short)(unsigned short)x;
}
// XOR swizzle for 128B-stride LDS rows: returns element-unit shift (units of 8 shorts = 16B slots)
DEVI int swz(int row) { return ((row ^ (row >> 3)) & 7) << 3; }

DEVI f32x4 mfma16(short8 a, short8 b, f32x4 c) {
    return __builtin_amdgcn_mfma_f32_16x16x32_bf16(a, b, c, 0, 0, 0);
}

// ---------------- supports: A = softmax(relu(E E^T), axis=1), bf16 out ----------------
__global__ __launch_bounds__(256) void k_supports(const float* __restrict__ NE,
                                                  short* __restrict__ A_bf) {
    int n = blockIdx.x, t = threadIdx.x;
    __shared__ float En[16];
    __shared__ float wsum[4];
    if (t < 16) En[t] = NE[n * 16 + t];
    __syncthreads();
    float e[4];
    float loc = 0.f;
#pragma unroll
    for (int i = 0; i < 4; ++i) {
        int m = t + 256 * i;
        const float* rp = NE + m * 16;
        float v = 0.f;
#pragma unroll
        for (int d = 0; d < 16; ++d) v += En[d] * rp[d];
        v = fmaxf(v, 0.f);
        e[i] = __expf(v);   // relu output in [0, ~2]: no max-subtract needed
        loc += e[i];
    }
#pragma unroll
    for (int off = 32; off; off >>= 1) loc += __shfl_xor(loc, off);
    if ((t & 63) == 0) wsum[t >> 6] = loc;
    __syncthreads();
    float inv = 1.f / (wsum[0] + wsum[1] + wsum[2] + wsum[3]);
#pragma unroll
    for (int i = 0; i < 4; ++i) A_bf[n * 1024 + t + 256 * i] = f2bf(e[i] * inv);
}

// ---------------- misc prep: B2 rows, xsum partials, s_bn, A2 rows ----------------
// B2[col=o*256+j][k64]: j<192 -> wp[d=k][kk=j>>6][i=j&63][o] in k=0..15 (rest 0)
//                       j>=192 -> wpa[d][kk][i2=j-192][o] in k=16+d*3+kk (rest 0)
// A2[n][k64]: k<16 -> E[n,k]; k=16+d*3+kk -> E[n,d]*diag_adj[kk][n]
__global__ __launch_bounds__(256) void k_small(
        const float* __restrict__ x, const float* __restrict__ xw,
        const float* __restrict__ NE, const float* __restrict__ adj,
        const float* __restrict__ wp, const float* __restrict__ wpa,
        const float* __restrict__ Tp,
        short* __restrict__ B2, short* __restrict__ A2,
        float* __restrict__ xsp, float* __restrict__ s_bn) {
    __shared__ float red[4][64];
    int bid = blockIdx.x, t = threadIdx.x;
    if (bid < 64) {  // B2 operand rows for o = bid
        int o = bid, j = t;
        short row[64];
        if (j < 192) {
            int kk = j >> 6, i = j & 63;
#pragma unroll
            for (int d = 0; d < 16; ++d)
                row[d] = f2bf(wp[((d * 3 + kk) * 64 + i) * 64 + o]);
#pragma unroll
            for (int k = 16; k < 64; ++k) row[k] = 0;
        } else {
            int i2 = j - 192;
#pragma unroll
            for (int k = 0; k < 16; ++k) row[k] = 0;
#pragma unroll
            for (int d = 0; d < 16; ++d)
#pragma unroll
                for (int kk = 0; kk < 3; ++kk)
                    row[16 + d * 3 + kk] = f2bf(wpa[((d * 3 + kk) * 64 + i2) * 64 + o]);
        }
        short* dst = B2 + (o * 256 + j) * 64;
#pragma unroll
        for (int q = 0; q < 8; ++q) {
            short8 v;
#pragma unroll
            for (int e2 = 0; e2 < 8; ++e2) v[e2] = row[q * 8 + e2];
            *reinterpret_cast<short8*>(dst + q * 8) = v;
        }
    } else if (bid < 320) {  // xsum partials: xsp[(b*4+mq)*64+c] = sum over 256 m
        int idx = bid - 64, b = idx >> 2, mq = idx & 3;
        int c = t & 63, q2 = t >> 6;
        int m0 = mq * 256 + q2 * 64;
        float s = 0.f;
        for (int mm = 0; mm < 64; ++mm) s += x[(b * 1024 + m0 + mm) * 64 + c];
        red[q2][c] = s;
        __syncthreads();
        if (t < 64) xsp[(b * 4 + mq) * 64 + t] = red[0][t] + red[1][t] + red[2][t] + red[3][t];
    } else if (bid < 336) {  // s_bn[b][n] = sum_t xw[b,t,n]*Tp[t]
        int idx = bid - 320;
        float tp[12];
#pragma unroll
        for (int i = 0; i < 12; ++i) tp[i] = Tp[i];
        for (int bb = 0; bb < 4; ++bb) {
            int b = idx * 4 + bb;
#pragma unroll
            for (int j2 = 0; j2 < 4; ++j2) {
                int nn = t + 256 * j2;
                float s = 0.f;
#pragma unroll
                for (int tt = 0; tt < 12; ++tt) s += xw[(b * 12 + tt) * 1024 + nn] * tp[tt];
                s_bn[b * 1024 + nn] = s;
            }
        }
    } else {  // A2 rows
        int n = (bid - 336) * 256 + t;
        float En[16];
#pragma unroll
        for (int d = 0; d < 16; ++d) En[d] = NE[n * 16 + d];
        float dg[3];
#pragma unroll
        for (int k = 0; k < 3; ++k) dg[k] = adj[k * 1024 * 1024 + n * 1024 + n];
        short row[64];
#pragma unroll
        for (int d = 0; d < 16; ++d) row[d] = f2bf(En[d]);
#pragma unroll
        for (int d = 0; d < 16; ++d)
#pragma unroll
            for (int k = 0; k < 3; ++k) row[16 + d * 3 + k] = f2bf(En[d] * dg[k]);
        short* dst = A2 + n * 64;
#pragma unroll
        for (int q = 0; q < 8; ++q) {
            short8 v;
#pragma unroll
            for (int e2 = 0; e2 < 8; ++e2) v[e2] = row[q * 8 + e2];
            *reinterpret_cast<short8*>(dst + q * 8) = v;
        }
    }
}

// ---------------- Wall = A2 (1024x64) @ B2^T : all per-node weights, bf16 ----------------
// Wall[n*16384 + o*256 + j]; j<192 = gconv W[n,k,i,o] (j=k*64+i); j>=192 = W2c[n,i,o]
__global__ __launch_bounds__(256) void k_gemm_w(const short* __restrict__ A2,
                                                const short* __restrict__ B2,
                                                short* __restrict__ Wall) {
    int bx = blockIdx.x, by = blockIdx.y;  // col-tile(128), row-tile(128)
    __shared__ __align__(16) short As[128 * 64];
    __shared__ __align__(16) short Bs[128 * 64];
    int t = threadIdx.x;
#pragma unroll
    for (int i = 0; i < 4; ++i) {
        int slot = t + 256 * i;
        int row = slot >> 3, k8 = slot & 7;
        int sw = swz(row);
        short8 va = *reinterpret_cast<const short8*>(A2 + (by * 128 + row) * 64 + k8 * 8);
        *reinterpret_cast<short8*>(&As[row * 64 + ((k8 * 8) ^ sw)]) = va;
        short8 vb = *reinterpret_cast<const short8*>(B2 + (bx * 128 + row) * 64 + k8 * 8);
        *reinterpret_cast<short8*>(&Bs[row * 64 + ((k8 * 8) ^ sw)]) = vb;
    }
    __syncthreads();
    int w = t >> 6, l = t & 63;
    int wm = w & 1, wn = w >> 1;
    int lr = l & 15, lg = l >> 4;
    f32x4 acc[4][4] = {};
#pragma unroll
    for (int ks = 0; ks < 2; ++ks) {
        int kk = ks * 32 + lg * 8;
        short8 af[4], bfr[4];
#pragma unroll
        for (int mf = 0; mf < 4; ++mf) {
            int row = wm * 64 + mf * 16 + lr;
            af[mf] = *reinterpret_cast<const short8*>(&As[row * 64 + (kk ^ swz(row))]);
        }
#pragma unroll
        for (int nf = 0; nf < 4; ++nf) {
            int row = wn * 64 + nf * 16 + lr;
            bfr[nf] = *reinterpret_cast<const short8*>(&Bs[row * 64 + (kk ^ swz(row))]);
        }
#pragma unroll
        for (int mf = 0; mf < 4; ++mf)
#pragma unroll
            for (int nf = 0; nf < 4; ++nf)
                acc[mf][nf] = mfma16(af[mf], bfr[nf], acc[mf][nf]);
    }
#pragma unroll
    for (int mf = 0; mf < 4; ++mf)
#pragma unroll
        for (int nf = 0; nf < 4; ++nf)
#pragma unroll
            for (int r = 0; r < 4; ++r) {
                int row = by * 128 + wm * 64 + mf * 16 + lg * 4 + r;
                int col = bx * 128 + wn * 64 + nf * 16 + lr;
                Wall[row * 16384 + col] = f2bf(acc[mf][nf][r]);
            }
}

// ---------------- y = A_bf (1024x1024) @ Bsrc[b] (1024x64), per-b, bf16 out ----------------
// BF32=1: Bsrc is f32 (x); BF32=0: Bsrc is bf16 (y1). B staged transposed into LDS.
template <int BF32>
__global__ __launch_bounds__(256) void k_gemm(const short* __restrict__ A_bf,
                                              const void* __restrict__ Bsrc,
                                              short* __restrict__ Crm) {
    int n0 = blockIdx.x * 128, b = blockIdx.y;
    __shared__ __align__(16) short As[128 * 64];
    __shared__ __align__(16) short Bs[64 * 64];
    int t = threadIdx.x;
    int w = t >> 6, l = t & 63;
    int wm = w & 1, wn = w >> 1;
    int lr = l & 15, lg = l >> 4;
    f32x4 acc[4][2] = {};
    const float* Bf = reinterpret_cast<const float*>(Bsrc) + b * 65536;
    const short* Bh = reinterpret_cast<const short*>(Bsrc) + b * 65536;
    int arow = t >> 3, ak8 = t & 7;
    int bc0 = (t & 7) * 8, bm = t >> 3;
    for (int kt = 0; kt < 16; ++kt) {
#pragma unroll
        for (int i = 0; i < 4; ++i) {
            int row = arow + 32 * i;
            short8 v = *reinterpret_cast<const short8*>(
                A_bf + (n0 + row) * 1024 + kt * 64 + ak8 * 8);
            *reinterpret_cast<short8*>(&As[row * 64 + ((ak8 * 8) ^ swz(row))]) = v;
        }
#pragma unroll
        for (int it = 0; it < 2; ++it) {
            int m = bm + 32 * it;
            if (BF32) {
                const float4* p = reinterpret_cast<const float4*>(Bf + (kt * 64 + m) * 64 + bc0);
                float4 p0 = p[0], p1 = p[1];
                float vv[8] = {p0.x, p0.y, p0.z, p0.w, p1.x, p1.y, p1.z, p1.w};
#pragma unroll
                for (int j = 0; j < 8; ++j) {
                    int c = bc0 + j;
                    Bs[c * 64 + (m ^ swz(c))] = f2bf(vv[j]);
                }
            } else {
                short8 hv = *reinterpret_cast<const short8*>(Bh + (kt * 64 + m) * 64 + bc0);
#pragma unroll
                for (int j = 0; j < 8; ++j) {
                    int c = bc0 + j;
                    Bs[c * 64 + (m ^ swz(c))] = hv[j];
                }
            }
        }
        __syncthreads();
#pragma unroll
        for (int ks = 0; ks < 2; ++ks) {
            int kk = ks * 32 + lg * 8;
            short8 af[4], bfr[2];
#pragma unroll
            for (int mf = 0; mf < 4; ++mf) {
                int row = wm * 64 + mf * 16 + lr;
                af[mf] = *reinterpret_cast<const short8*>(&As[row * 64 + (kk ^ swz(row))]);
            }
#pragma unroll
            for (int nf = 0; nf < 2; ++nf) {
                int c = wn * 32 + nf * 16 + lr;
                bfr[nf] = *reinterpret_cast<const short8*>(&Bs[c * 64 + (kk ^ swz(c))]);
            }
#pragma unroll
            for (int mf = 0; mf < 4; ++mf)
#pragma unroll
                for (int nf = 0; nf < 2; ++nf)
                    acc[mf][nf] = mfma16(af[mf], bfr[nf], acc[mf][nf]);
        }
        __syncthreads();
    }
#pragma unroll
    for (int mf = 0; mf < 4; ++mf)
#pragma unroll
        for (int nf = 0; nf < 2; ++nf)
#pragma unroll
            for (int r = 0; r < 4; ++r) {
                int nrow = n0 + wm * 64 + mf * 16 + lg * 4 + r;
                int c = wn * 32 + nf * 16 + lr;
                Crm[(b * 1024 + nrow) * 64 + c] = f2bf(acc[mf][nf][r]);
            }
}

// ---------------- epilogue: per-node MFMA (M=64 batch, N=64 O, K=256) + norms + bias ----------------
__global__ __launch_bounds__(256) void k_epi(
        const float* __restrict__ x, const short* __restrict__ y1,
        const short* __restrict__ y2, const float* __restrict__ xsp,
        const float* __restrict__ s_bn, const short* __restrict__ Wall,
        const float* __restrict__ NE, const float* __restrict__ bp,
        const float* __restrict__ wwin, float* __restrict__ out) {
    int n = blockIdx.x, t = threadIdx.x;
    __shared__ __align__(16) short Ylds[64 * 256];
    __shared__ float E_l[16];
    __shared__ float bias_l[192];
    __shared__ float ww_l[64];
    __shared__ float sq_l[2][2][64];
    __shared__ float wwn_l;
    if (t < 16) E_l[t] = NE[n * 16 + t];
    __syncthreads();
    if (t < 192) {
        float s = 0.f;
#pragma unroll
        for (int d = 0; d < 16; ++d) s += E_l[d] * bp[d * 192 + t];
        bias_l[t] = s;
    } else {
        int o = t - 192;
        float s = 0.f;
#pragma unroll
        for (int d = 0; d < 16; ++d) s += E_l[d] * wwin[d * 64 + o];
        ww_l[o] = s;
    }
    int w = t >> 6, l = t & 63;
    int wm = w & 1, wn = w >> 1;
    int lr = l & 15, lg = l >> 4;
    // hold W fragments in VGPRs (B-operand: lane col=o, k=j)
    short8 wf[8][2];
#pragma unroll
    for (int ks = 0; ks < 8; ++ks)
#pragma unroll
        for (int nf = 0; nf < 2; ++nf) {
            int o = wn * 32 + nf * 16 + lr;
            int k = ks * 32 + lg * 8;
            wf[ks][nf] = *reinterpret_cast<const short8*>(Wall + (n * 64 + o) * 256 + k);
        }
    // stage Ylds[b][j]: j = [x | y1 | y2 | xsum], swizzled
    for (int it = 0; it < 16; ++it) {
        int b = it * 4 + (t >> 6);
        int c = t & 63;
        int sw = swz(b);
        int base = b * 256;
        float xv = x[(b * 1024 + n) * 64 + c];
        short y1v = y1[(b * 1024 + n) * 64 + c];
        short y2v = y2[(b * 1024 + n) * 64 + c];
        float xs = xsp[(b * 4 + 0) * 64 + c] + xsp[(b * 4 + 1) * 64 + c] +
                   xsp[(b * 4 + 2) * 64 + c] + xsp[(b * 4 + 3) * 64 + c];
        Ylds[base + ((0 * 64 + c) ^ sw)] = f2bf(xv);
        Ylds[base + ((1 * 64 + c) ^ sw)] = y1v;
        Ylds[base + ((2 * 64 + c) ^ sw)] = y2v;
        Ylds[base + ((3 * 64 + c) ^ sw)] = f2bf(xs);
    }
    __syncthreads();
    if (t < 64) {  // ||ww||
        float v = ww_l[t];
        float s2 = v * v;
#pragma unroll
        for (int off = 32; off; off >>= 1) s2 += __shfl_xor(s2, off);
        if (t == 0) wwn_l = sqrtf(s2);
    }
    f32x4 accg[2][2] = {};
    f32x4 acca[2][2] = {};
#pragma unroll
    for (int ks = 0; ks < 8; ++ks) {
        short8 af[2];
#pragma unroll
        for (int mf = 0; mf < 2; ++mf) {
            int b = wm * 32 + mf * 16 + lr;
            int k = ks * 32 + lg * 8;
            af[mf] = *reinterpret_cast<const short8*>(&Ylds[b * 256 + (k ^ swz(b))]);
        }
#pragma unroll
        for (int mf = 0; mf < 2; ++mf)
#pragma unroll
            for (int nf = 0; nf < 2; ++nf) {
                if (ks < 6) accg[mf][nf] = mfma16(af[mf], wf[ks][nf], accg[mf][nf]);
                else        acca[mf][nf] = mfma16(af[mf], wf[ks][nf], acca[mf][nf]);
            }
    }
    // per-b-row sum of squares (within 16-lane col groups), combine wn halves via LDS
#pragma unroll
    for (int mf = 0; mf < 2; ++mf)
#pragma unroll
        for (int r = 0; r < 4; ++r) {
            float sg = accg[mf][0][r] * accg[mf][0][r] + accg[mf][1][r] * accg[mf][1][r];
            float sa = acca[mf][0][r] * acca[mf][0][r] + acca[mf][1][r] * acca[mf][1][r];
#pragma unroll
            for (int off = 1; off < 16; off <<= 1) {
                sg += __shfl_xor(sg, off);
                sa += __shfl_xor(sa, off);
            }
            if (lr == 0) {
                int b = wm * 32 + mf * 16 + lg * 4 + r;
                sq_l[0][wn][b] = sg;
                sq_l[1][wn][b] = sa;
            }
        }
    __syncthreads();
#pragma unroll
    for (int mf = 0; mf < 2; ++mf)
#pragma unroll
        for (int r = 0; r < 4; ++r) {
            int b = wm * 32 + mf * 16 + lg * 4 + r;
            float ig = 1.f / fmaxf(sqrtf(sq_l[0][0][b] + sq_l[0][1][b]), 1e-12f);
            float ia = 1.f / fmaxf(sqrtf(sq_l[1][0][b] + sq_l[1][1][b]), 1e-12f);
            float* po = out + (b * 1024 + n) * 192;
#pragma unroll
            for (int nf = 0; nf < 2; ++nf) {
                int o = wn * 32 + nf * 16 + lr;
                po[o]      = accg[mf][nf][r] * ig + bias_l[o];
                po[64 + o] = acca[mf][nf][r] * ia + bias_l[64 + o];
            }
        }
    // wconv: out3 = s*ww/max(|s|*||ww||, eps)
    float wwn = wwn_l;
    for (int it = 0; it < 16; ++it) {
        int b = it * 4 + (t >> 6);
        int o = t & 63;
        float s = s_bn[b * 1024 + n];
        float pre = s * ww_l[o];
        float nrm = fabsf(s) * wwn;
        out[(b * 1024 + n) * 192 + 128 + o] = pre / fmaxf(nrm, 1e-12f) + bias_l[128 + o];
    }
}

extern "C" void kernel_launch(void* const* d_in, const int* in_sizes, int n_in,
                              void* d_out, int out_size, void* d_ws, size_t ws_size,
                              hipStream_t stream) {
    const float* x    = (const float*)d_in[0];
    const float* xw   = (const float*)d_in[1];
    const float* NE   = (const float*)d_in[2];
    // d_in[3] = ZPI (unused by reference)
    const float* adj  = (const float*)d_in[4];
    const float* wp   = (const float*)d_in[5];
    const float* wpa  = (const float*)d_in[6];
    const float* wwin = (const float*)d_in[7];
    const float* bp   = (const float*)d_in[8];
    const float* Tp   = (const float*)d_in[9];
    float* out = (float*)d_out;

    char* ws = (char*)d_ws;
    const size_t OFF_ABF  = 0;          // 1024*1024*2 = 2 MB
    const size_t OFF_Y1   = 2097152;    // 8 MB
    const size_t OFF_Y2   = 10485760;   // 8 MB
    const size_t OFF_WALL = 18874368;   // 32 MB
    const size_t OFF_A2   = 52428800;   // 128 KB
    const size_t OFF_B2   = 52559872;   // 2 MB
    const size_t OFF_XSP  = 54657024;   // 64 KB
    const size_t OFF_SBN  = 54722560;   // 256 KB
    const size_t NEED     = 54984704;
    if (ws_size < NEED) return;  // will fail validation loudly

    short* A_bf = (short*)(ws + OFF_ABF);
    short* y1   = (short*)(ws + OFF_Y1);
    short* y2   = (short*)(ws + OFF_Y2);
    short* Wall = (short*)(ws + OFF_WALL);
    short* A2   = (short*)(ws + OFF_A2);
    short* B2   = (short*)(ws + OFF_B2);
    float* xsp  = (float*)(ws + OFF_XSP);
    float* s_bn = (float*)(ws + OFF_SBN);

    k_supports<<<1024, 256, 0, stream>>>(NE, A_bf);
    k_small<<<340, 256, 0, stream>>>(x, xw, NE, adj, wp, wpa, Tp, B2, A2, xsp, s_bn);
    k_gemm_w<<<dim3(128, 8), 256, 0, stream>>>(A2, B2, Wall);
    k_gemm<1><<<dim3(8, 64), 256, 0, stream>>>(A_bf, (const void*)x, y1);
    k_gemm<0><<<dim3(8, 64), 256, 0, stream>>>(A_bf, (const void*)y1, y2);
    k_epi<<<1024, 256, 0, stream>>>(x, y1, y2, xsp, s_bn, Wall, NE, bp, wwin, out);
}